// Round 5
// baseline (838.763 us; speedup 1.0000x reference)
//
#include <hip/hip_runtime.h>
#include <hip/hip_cooperative_groups.h>
#include <math.h>

namespace cg = cooperative_groups;

#define HD 4096
#define LD 2048

// ---------------- reduction helpers ----------------
__device__ __forceinline__ float wave_sum(float v) {
#pragma unroll
    for (int off = 32; off > 0; off >>= 1) v += __shfl_down(v, off, 64);
    return v;
}
__device__ __forceinline__ float wave_max(float v) {
#pragma unroll
    for (int off = 32; off > 0; off >>= 1) v = fmaxf(v, __shfl_down(v, off, 64));
    return v;
}
__device__ __forceinline__ float block_sum256(float v, float* sm) {
    v = wave_sum(v);
    if ((threadIdx.x & 63) == 0) sm[threadIdx.x >> 6] = v;
    __syncthreads();
    float r = sm[0] + sm[1] + sm[2] + sm[3];
    __syncthreads();
    return r;
}
__device__ __forceinline__ float block_max256(float v, float* sm) {
    v = wave_max(v);
    if ((threadIdx.x & 63) == 0) sm[threadIdx.x >> 6] = v;
    __syncthreads();
    float r = fmaxf(fmaxf(sm[0], sm[1]), fmaxf(sm[2], sm[3]));
    __syncthreads();
    return r;
}

// per-thread partial dots (256-thread blocks)
__device__ __forceinline__ float pdot4096(const float4* __restrict__ W4,
                                          const float4* __restrict__ X4, int t) {
    float a0 = 0.f, a1 = 0.f;
#pragma unroll
    for (int i = 0; i < 4; i += 2) {
        int idx = i * 256 + t;
        float4 w = W4[idx], x = X4[idx];
        a0 = fmaf(w.x, x.x, a0); a0 = fmaf(w.y, x.y, a0);
        a0 = fmaf(w.z, x.z, a0); a0 = fmaf(w.w, x.w, a0);
        int idx2 = idx + 256;
        float4 w2 = W4[idx2], x2 = X4[idx2];
        a1 = fmaf(w2.x, x2.x, a1); a1 = fmaf(w2.y, x2.y, a1);
        a1 = fmaf(w2.z, x2.z, a1); a1 = fmaf(w2.w, x2.w, a1);
    }
    return a0 + a1;
}
__device__ __forceinline__ float pdot8192(const float4* __restrict__ W4,
                                          const float4* __restrict__ X1,
                                          const float4* __restrict__ X2, int t) {
    float a0 = 0.f, a1 = 0.f;
#pragma unroll
    for (int i = 0; i < 4; ++i) {
        int idx = i * 256 + t;
        float4 w = W4[idx], x = X1[idx];
        a0 = fmaf(w.x, x.x, a0); a0 = fmaf(w.y, x.y, a0);
        a0 = fmaf(w.z, x.z, a0); a0 = fmaf(w.w, x.w, a0);
        int idx2 = idx + 1024;
        float4 w2 = W4[idx2], x2 = X2[idx];
        a1 = fmaf(w2.x, x2.x, a1); a1 = fmaf(w2.y, x2.y, a1);
        a1 = fmaf(w2.z, x2.z, a1); a1 = fmaf(w2.w, x2.w, a1);
    }
    return a0 + a1;
}

struct Params {
    const int* token; const float* h; const float* c; const float* enc; const float* emb;
    const float* Wattn; const float* battn; const float* Wcomb; const float* bcomb;
    const float* Wih; const float* Whh; const float* bih; const float* bhh;
    const float* Wout; const float* bout;
    float* out; float* attn_logits; float* ghh; float* ctx; float* xvec;
    float* logits; float* partial;
};

// =========================== fused cooperative kernel ===========================
__global__ __launch_bounds__(256, 4) void fused_decoder(Params p)
{
    cg::grid_group grid = cg::this_grid();
    const int t = threadIdx.x, bid = blockIdx.x, G = gridDim.x;
    __shared__ float sm4[4];
    __shared__ float sm44[4][4];
    __shared__ float smw[2048];
    __shared__ float4 red[4][64];

    const float* e = p.emb + (size_t)p.token[0] * HD;
    const float4* E1 = reinterpret_cast<const float4*>(e);
    const float4* H4 = reinterpret_cast<const float4*>(p.h);

    // ---- S1: attn logits (64 MB) + gates_hh (256 MB) ----
    for (int r = bid; r < LD; r += G) {
        float v = pdot8192(reinterpret_cast<const float4*>(p.Wattn + (size_t)r * 8192), E1, H4, t);
        v = wave_sum(v);
        if ((t & 63) == 0) sm4[t >> 6] = v;
        __syncthreads();
        if (t == 0) p.attn_logits[r] = sm4[0] + sm4[1] + sm4[2] + sm4[3] + p.battn[r];
        __syncthreads();
    }
    for (int r = bid; r < 4 * HD; r += G) {
        float v = pdot4096(reinterpret_cast<const float4*>(p.Whh + (size_t)r * HD), H4, t);
        v = wave_sum(v);
        if ((t & 63) == 0) sm4[t >> 6] = v;
        __syncthreads();
        if (t == 0) p.ghh[r] = sm4[0] + sm4[1] + sm4[2] + sm4[3] + p.bih[r] + p.bhh[r];
        __syncthreads();
    }
    __threadfence();
    grid.sync();

    // ---- S2: redundant softmax per block + coalesced ctx-partial (32 MB) ----
    {
        float vals[8];
        float m = -INFINITY;
#pragma unroll
        for (int i = 0; i < 8; ++i) { vals[i] = p.attn_logits[i * 256 + t]; m = fmaxf(m, vals[i]); }
        m = block_max256(m, sm4);
        float s = 0.f;
#pragma unroll
        for (int i = 0; i < 8; ++i) { vals[i] = expf(vals[i] - m); s += vals[i]; }
        s = block_sum256(s, sm4);
        const float inv = 1.f / s;
#pragma unroll
        for (int i = 0; i < 8; ++i) smw[i * 256 + t] = vals[i] * inv;
        __syncthreads();
        if (bid == 0) {
#pragma unroll
            for (int i = 0; i < 8; ++i) p.out[3 * HD + i * 256 + t] = smw[i * 256 + t];
        }
        const float4* E4 = reinterpret_cast<const float4*>(p.enc);
        for (int task = bid; task < 1024; task += G) {
            const int rc = task >> 4, cc = task & 15;
            const int g = t >> 6, lc = t & 63;
            const int c4 = (cc << 6) + lc;
            const int r0 = rc * 32 + g * 8;
            float4 acc = make_float4(0.f, 0.f, 0.f, 0.f);
#pragma unroll
            for (int k = 0; k < 8; ++k) {
                float wv = smw[r0 + k];
                float4 ev = E4[(size_t)(r0 + k) * 1024 + c4];
                acc.x = fmaf(wv, ev.x, acc.x); acc.y = fmaf(wv, ev.y, acc.y);
                acc.z = fmaf(wv, ev.z, acc.z); acc.w = fmaf(wv, ev.w, acc.w);
            }
            red[g][lc] = acc;
            __syncthreads();
            if (t < 64) {
                float4 s2 = red[0][t];
#pragma unroll
                for (int k = 1; k < 4; ++k) {
                    float4 v = red[k][t];
                    s2.x += v.x; s2.y += v.y; s2.z += v.z; s2.w += v.w;
                }
                reinterpret_cast<float4*>(p.partial)[(size_t)rc * 1024 + (cc << 6) + t] = s2;
            }
            __syncthreads();
        }
    }
    __threadfence();
    grid.sync();

    // ---- S3: ctx = column sum of 64 partials (1 MB, L2) ----
    for (int gid = bid * 256 + t; gid < HD; gid += G * 256) {
        float s = 0.f;
#pragma unroll 8
        for (int k = 0; k < 64; ++k) s += p.partial[(size_t)k * HD + gid];
        p.ctx[gid] = s;
    }
    __threadfence();
    grid.sync();

    // ---- S4: x = relu(W_comb · cat(e, ctx) + b) (128 MB) ----
    {
        const float4* C4 = reinterpret_cast<const float4*>(p.ctx);
        for (int r = bid; r < HD; r += G) {
            float v = pdot8192(reinterpret_cast<const float4*>(p.Wcomb + (size_t)r * 8192), E1, C4, t);
            v = wave_sum(v);
            if ((t & 63) == 0) sm4[t >> 6] = v;
            __syncthreads();
            if (t == 0) p.xvec[r] = fmaxf(sm4[0] + sm4[1] + sm4[2] + sm4[3] + p.bcomb[r], 0.f);
            __syncthreads();
        }
    }
    __threadfence();
    grid.sync();

    // ---- S5: gates_ih + LSTM cell (256 MB) ----
    {
        const float4* X4 = reinterpret_cast<const float4*>(p.xvec);
        for (int j = bid; j < HD; j += G) {
            float acc[4];
#pragma unroll
            for (int g = 0; g < 4; ++g)
                acc[g] = pdot4096(reinterpret_cast<const float4*>(p.Wih + (size_t)(g * HD + j) * HD), X4, t);
#pragma unroll
            for (int g = 0; g < 4; ++g) {
                float v = wave_sum(acc[g]);
                if ((t & 63) == 0) sm44[t >> 6][g] = v;
            }
            __syncthreads();
            if (t == 0) {
                float gi = sm44[0][0] + sm44[1][0] + sm44[2][0] + sm44[3][0] + p.ghh[j];
                float gf = sm44[0][1] + sm44[1][1] + sm44[2][1] + sm44[3][1] + p.ghh[HD + j];
                float gg = sm44[0][2] + sm44[1][2] + sm44[2][2] + sm44[3][2] + p.ghh[2 * HD + j];
                float go = sm44[0][3] + sm44[1][3] + sm44[2][3] + sm44[3][3] + p.ghh[3 * HD + j];
                float si = 1.f / (1.f + expf(-gi));
                float sf = 1.f / (1.f + expf(-gf));
                float so = 1.f / (1.f + expf(-go));
                float cn = sf * p.c[j] + si * tanhf(gg);
                float hn = so * tanhf(cn);
                p.out[HD + j] = hn;
                p.out[2 * HD + j] = cn;
            }
            __syncthreads();
        }
    }
    __threadfence();
    grid.sync();

    // ---- S6: logits = W_out · h_new + b_out (64 MB) ----
    {
        const float4* HN4 = reinterpret_cast<const float4*>(p.out + HD);
        for (int r = bid; r < HD; r += G) {
            float v = pdot4096(reinterpret_cast<const float4*>(p.Wout + (size_t)r * HD), HN4, t);
            v = wave_sum(v);
            if ((t & 63) == 0) sm4[t >> 6] = v;
            __syncthreads();
            if (t == 0) p.logits[r] = sm4[0] + sm4[1] + sm4[2] + sm4[3] + p.bout[r];
            __syncthreads();
        }
    }
    __threadfence();
    grid.sync();

    // ---- S7: log_softmax (block 0) ----
    if (bid == 0) {
        float vals[16];
        float m = -INFINITY;
#pragma unroll
        for (int i = 0; i < 16; ++i) { vals[i] = p.logits[i * 256 + t]; m = fmaxf(m, vals[i]); }
        m = block_max256(m, sm4);
        float s = 0.f;
#pragma unroll
        for (int i = 0; i < 16; ++i) s += expf(vals[i] - m);
        s = block_sum256(s, sm4);
        float lse = m + logf(s);
#pragma unroll
        for (int i = 0; i < 16; ++i) p.out[i * 256 + t] = vals[i] - lse;
    }
}

// =========================== fallback kernels (R4 set) ===========================
__device__ __forceinline__ void hh_row(
    int r, const float* __restrict__ Whh, const float* __restrict__ bih,
    const float* __restrict__ bhh, const float* __restrict__ h,
    float* __restrict__ ghh)
{
    const int t = threadIdx.x;
    float v = pdot4096(reinterpret_cast<const float4*>(Whh + (size_t)r * HD),
                       reinterpret_cast<const float4*>(h), t);
    __shared__ float smr[4];
    float acc = wave_sum(v);
    if ((t & 63) == 0) smr[t >> 6] = acc;
    __syncthreads();
    if (t == 0) ghh[r] = smr[0] + smr[1] + smr[2] + smr[3] + bih[r] + bhh[r];
}

__global__ __launch_bounds__(256) void k1_attn_hh(
    const float* __restrict__ Wattn, const float* __restrict__ battn,
    const float* __restrict__ emb, const int* __restrict__ token,
    const float* __restrict__ h,
    const float* __restrict__ Whh, const float* __restrict__ bih,
    const float* __restrict__ bhh,
    float* __restrict__ attn_logits, float* __restrict__ ghh)
{
    const int bx = blockIdx.x;
    const int t = threadIdx.x;
    if (bx < LD) {
        const float* x1 = emb + (size_t)token[0] * HD;
        float v = pdot8192(reinterpret_cast<const float4*>(Wattn + (size_t)bx * 8192),
                           reinterpret_cast<const float4*>(x1),
                           reinterpret_cast<const float4*>(h), t);
        __shared__ float sm[4];
        float acc = wave_sum(v);
        if ((t & 63) == 0) sm[t >> 6] = acc;
        __syncthreads();
        if (t == 0) attn_logits[bx] = sm[0] + sm[1] + sm[2] + sm[3] + battn[bx];
    } else {
        hh_row(bx - LD, Whh, bih, bhh, h, ghh);
    }
}

__global__ __launch_bounds__(256) void k2_ctx_hh(
    const float* __restrict__ logits, const float* __restrict__ enc,
    const float* __restrict__ Whh, const float* __restrict__ bih,
    const float* __restrict__ bhh, const float* __restrict__ h,
    float* __restrict__ ctx, float* __restrict__ attn_out, float* __restrict__ ghh)
{
    const int bx = blockIdx.x;
    const int t = threadIdx.x;
    if (bx <= 64) {
        __shared__ float sm[4];
        float vals[8];
        float m = -INFINITY;
#pragma unroll
        for (int i = 0; i < 8; ++i) { vals[i] = logits[i * 256 + t]; m = fmaxf(m, vals[i]); }
        m = block_max256(m, sm);
        float s = 0.f;
#pragma unroll
        for (int i = 0; i < 8; ++i) { vals[i] = expf(vals[i] - m); s += vals[i]; }
        s = block_sum256(s, sm);
        const float inv = 1.f / s;
        if (bx == 64) {
#pragma unroll
            for (int i = 0; i < 8; ++i) attn_out[i * 256 + t] = vals[i] * inv;
            return;
        }
        __shared__ float smw[2048];
#pragma unroll
        for (int i = 0; i < 8; ++i) smw[i * 256 + t] = vals[i] * inv;
        __syncthreads();
        const int rg = t >> 4;
        const int cc = t & 15;
        const int col4 = bx * 16 + cc;
        const float4* E = reinterpret_cast<const float4*>(enc);
        float4 acc = make_float4(0.f, 0.f, 0.f, 0.f);
        const int k0 = rg * 128;
#pragma unroll 8
        for (int k = k0; k < k0 + 128; ++k) {
            float wv = smw[k];
            float4 ev = E[(size_t)k * 1024 + col4];
            acc.x = fmaf(wv, ev.x, acc.x); acc.y = fmaf(wv, ev.y, acc.y);
            acc.z = fmaf(wv, ev.z, acc.z); acc.w = fmaf(wv, ev.w, acc.w);
        }
        __shared__ float4 red[16][16];
        red[rg][cc] = acc;
        __syncthreads();
        if (t < 16) {
            float4 s2 = red[0][t];
#pragma unroll
            for (int k = 1; k < 16; ++k) {
                float4 v = red[k][t];
                s2.x += v.x; s2.y += v.y; s2.z += v.z; s2.w += v.w;
            }
            reinterpret_cast<float4*>(ctx)[bx * 16 + t] = s2;
        }
    } else {
        hh_row(4096 + (bx - 65), Whh, bih, bhh, h, ghh);
    }
}

__global__ __launch_bounds__(256) void k3_comb_hh(
    const float* __restrict__ W, const float* __restrict__ bias,
    const float* __restrict__ emb, const int* __restrict__ token,
    const float* __restrict__ ctx,
    const float* __restrict__ Whh, const float* __restrict__ bih,
    const float* __restrict__ bhh, const float* __restrict__ h,
    float* __restrict__ xvec, float* __restrict__ ghh)
{
    const int bx = blockIdx.x;
    const int t = threadIdx.x;
    if (bx < HD) {
        const float* x1 = emb + (size_t)token[0] * HD;
        float v = pdot8192(reinterpret_cast<const float4*>(W + (size_t)bx * 8192),
                           reinterpret_cast<const float4*>(x1),
                           reinterpret_cast<const float4*>(ctx), t);
        __shared__ float sm[4];
        float acc = wave_sum(v);
        if ((t & 63) == 0) sm[t >> 6] = acc;
        __syncthreads();
        if (t == 0) xvec[bx] = fmaxf(sm[0] + sm[1] + sm[2] + sm[3] + bias[bx], 0.f);
    } else {
        hh_row(10240 + (bx - HD), Whh, bih, bhh, h, ghh);
    }
}

__global__ __launch_bounds__(256) void k4_ih_cell(
    const float* __restrict__ Wih, const float* __restrict__ ghh,
    const float* __restrict__ x, const float* __restrict__ c,
    float* __restrict__ out)
{
    const int j = blockIdx.x;
    const int t = threadIdx.x;
    const float4* X = reinterpret_cast<const float4*>(x);
    float acc[4];
#pragma unroll
    for (int g = 0; g < 4; ++g)
        acc[g] = pdot4096(reinterpret_cast<const float4*>(Wih + (size_t)(g * HD + j) * HD), X, t);
    __shared__ float sm[4][4];
#pragma unroll
    for (int g = 0; g < 4; ++g) {
        float v = wave_sum(acc[g]);
        if ((t & 63) == 0) sm[t >> 6][g] = v;
    }
    __syncthreads();
    if (t == 0) {
        float gi = sm[0][0] + sm[1][0] + sm[2][0] + sm[3][0] + ghh[j];
        float gf = sm[0][1] + sm[1][1] + sm[2][1] + sm[3][1] + ghh[HD + j];
        float gg = sm[0][2] + sm[1][2] + sm[2][2] + sm[3][2] + ghh[2 * HD + j];
        float go = sm[0][3] + sm[1][3] + sm[2][3] + sm[3][3] + ghh[3 * HD + j];
        float si = 1.f / (1.f + expf(-gi));
        float sf = 1.f / (1.f + expf(-gf));
        float so = 1.f / (1.f + expf(-go));
        float cn = sf * c[j] + si * tanhf(gg);
        float hn = so * tanhf(cn);
        out[HD + j] = hn;
        out[2 * HD + j] = cn;
    }
}

__global__ __launch_bounds__(256) void k5_out(
    const float* __restrict__ W, const float* __restrict__ bias,
    const float* __restrict__ x, float* __restrict__ out)
{
    const int row = blockIdx.x;
    const int t = threadIdx.x;
    float v = pdot4096(reinterpret_cast<const float4*>(W + (size_t)row * HD),
                       reinterpret_cast<const float4*>(x), t);
    __shared__ float sm[4];
    float acc = wave_sum(v);
    if ((t & 63) == 0) sm[t >> 6] = acc;
    __syncthreads();
    if (t == 0) out[row] = sm[0] + sm[1] + sm[2] + sm[3] + bias[row];
}

__global__ __launch_bounds__(1024) void k6_logsoftmax(
    const float* __restrict__ logits, float* __restrict__ out)
{
    __shared__ float sm[16];
    const int t = threadIdx.x;
    float vals[4];
    float m = -INFINITY;
#pragma unroll
    for (int i = 0; i < 4; ++i) { vals[i] = logits[i * 1024 + t]; m = fmaxf(m, vals[i]); }
    m = wave_max(m);
    if ((t & 63) == 0) sm[t >> 6] = m;
    __syncthreads();
    float mm = -INFINITY;
#pragma unroll
    for (int k = 0; k < 16; ++k) mm = fmaxf(mm, sm[k]);
    __syncthreads();
    float s = 0.f;
#pragma unroll
    for (int i = 0; i < 4; ++i) s += expf(vals[i] - mm);
    s = wave_sum(s);
    if ((t & 63) == 0) sm[t >> 6] = s;
    __syncthreads();
    float ss = 0.f;
#pragma unroll
    for (int k = 0; k < 16; ++k) ss += sm[k];
    float lse = mm + logf(ss);
#pragma unroll
    for (int i = 0; i < 4; ++i) out[i * 1024 + t] = vals[i] - lse;
}

extern "C" void kernel_launch(void* const* d_in, const int* in_sizes, int n_in,
                              void* d_out, int out_size, void* d_ws, size_t ws_size,
                              hipStream_t stream)
{
    const int*   token  = (const int*)  d_in[0];
    const float* h      = (const float*)d_in[1];
    const float* c      = (const float*)d_in[2];
    const float* enc    = (const float*)d_in[3];
    const float* emb    = (const float*)d_in[4];
    const float* W_attn = (const float*)d_in[5];
    const float* b_attn = (const float*)d_in[6];
    const float* W_comb = (const float*)d_in[7];
    const float* b_comb = (const float*)d_in[8];
    const float* W_ih   = (const float*)d_in[9];
    const float* W_hh   = (const float*)d_in[10];
    const float* b_ih   = (const float*)d_in[11];
    const float* b_hh   = (const float*)d_in[12];
    const float* W_out  = (const float*)d_in[13];
    const float* b_out  = (const float*)d_in[14];
    float* out = (float*)d_out;  // [logp 4096 | h_new 4096 | c_new 4096 | attn_w 2048]

    // ws layout (floats): all offsets 16B-aligned
    float* ws          = (float*)d_ws;
    float* attn_logits = ws;               // 2048
    float* ghh         = ws + 2048;        // 16384
    float* ctx         = ws + 18432;       // 4096
    float* xvec        = ws + 22528;       // 4096
    float* logits      = ws + 26624;       // 4096
    float* partial     = ws + 30720;       // 64*4096 = 262144

    // ---- cooperative single-kernel path ----
    int dev = 0;
    hipGetDevice(&dev);
    int coop = 0;
    hipDeviceGetAttribute(&coop, hipDeviceAttributeCooperativeLaunch, dev);
    int ncu = 0;
    hipDeviceGetAttribute(&ncu, hipDeviceAttributeMultiprocessorCount, dev);
    int maxb = 0;
    hipOccupancyMaxActiveBlocksPerMultiprocessor(&maxb, fused_decoder, 256, 0);
    int G = maxb * ncu;
    if (G > 1024) G = 1024;

    if (coop && G >= 64) {
        Params P;
        P.token = token; P.h = h; P.c = c; P.enc = enc; P.emb = emb;
        P.Wattn = W_attn; P.battn = b_attn; P.Wcomb = W_comb; P.bcomb = b_comb;
        P.Wih = W_ih; P.Whh = W_hh; P.bih = b_ih; P.bhh = b_hh;
        P.Wout = W_out; P.bout = b_out;
        P.out = out; P.attn_logits = attn_logits; P.ghh = ghh; P.ctx = ctx;
        P.xvec = xvec; P.logits = logits; P.partial = partial;
        void* args[] = { &P };
        hipLaunchCooperativeKernel((void*)fused_decoder, dim3(G), dim3(256), args, 0, stream);
        return;
    }

    // ---- fallback: 6-kernel path (R4) ----
    k1_attn_hh<<<LD + 4096, 256, 0, stream>>>(
        W_attn, b_attn, emb, token, h, W_hh, b_ih, b_hh, attn_logits, ghh);
    k2_ctx_hh<<<65 + 6144, 256, 0, stream>>>(
        attn_logits, enc, W_hh, b_ih, b_hh, h, ctx, out + 3 * HD, ghh);
    k3_comb_hh<<<HD + 6144, 256, 0, stream>>>(
        W_comb, b_comb, emb, token, ctx, W_hh, b_ih, b_hh, h, xvec, ghh);
    k4_ih_cell<<<HD, 256, 0, stream>>>(W_ih, ghh, xvec, c, out);
    k5_out<<<HD, 256, 0, stream>>>(W_out, b_out, out + HD, logits);
    k6_logsoftmax<<<1, 1024, 0, stream>>>(logits, out);
}

// Round 6
// 159.504 us; speedup vs baseline: 5.2586x; 5.2586x over previous
//
#include <hip/hip_runtime.h>
#include <math.h>

#define HD 4096
#define LD 2048

// ---------------- reduction helpers ----------------
__device__ __forceinline__ float wave_sum(float v) {
#pragma unroll
    for (int off = 32; off > 0; off >>= 1) v += __shfl_down(v, off, 64);
    return v;
}
__device__ __forceinline__ float wave_max(float v) {
#pragma unroll
    for (int off = 32; off > 0; off >>= 1) v = fmaxf(v, __shfl_down(v, off, 64));
    return v;
}
__device__ __forceinline__ float block_sum256(float v, float* sm) {
    v = wave_sum(v);
    if ((threadIdx.x & 63) == 0) sm[threadIdx.x >> 6] = v;
    __syncthreads();
    float r = sm[0] + sm[1] + sm[2] + sm[3];
    __syncthreads();
    return r;
}
__device__ __forceinline__ float block_max256(float v, float* sm) {
    v = wave_max(v);
    if ((threadIdx.x & 63) == 0) sm[threadIdx.x >> 6] = v;
    __syncthreads();
    float r = fmaxf(fmaxf(sm[0], sm[1]), fmaxf(sm[2], sm[3]));
    __syncthreads();
    return r;
}

// ---------------- per-WAVE dot products (lane l of a 64-lane wave) ----------------
// row of 4096 floats = 1024 float4; lane reads 16 float4 (idx = i*64 + l)
__device__ __forceinline__ float wdot4096(const float4* __restrict__ W4,
                                          const float4* __restrict__ X4, int l) {
    float a0 = 0.f, a1 = 0.f, a2 = 0.f, a3 = 0.f;
#pragma unroll
    for (int i = 0; i < 16; i += 4) {
        float4 w0 = W4[(i + 0) * 64 + l], x0 = X4[(i + 0) * 64 + l];
        float4 w1 = W4[(i + 1) * 64 + l], x1 = X4[(i + 1) * 64 + l];
        float4 w2 = W4[(i + 2) * 64 + l], x2 = X4[(i + 2) * 64 + l];
        float4 w3 = W4[(i + 3) * 64 + l], x3 = X4[(i + 3) * 64 + l];
        a0 = fmaf(w0.x, x0.x, a0); a0 = fmaf(w0.y, x0.y, a0);
        a0 = fmaf(w0.z, x0.z, a0); a0 = fmaf(w0.w, x0.w, a0);
        a1 = fmaf(w1.x, x1.x, a1); a1 = fmaf(w1.y, x1.y, a1);
        a1 = fmaf(w1.z, x1.z, a1); a1 = fmaf(w1.w, x1.w, a1);
        a2 = fmaf(w2.x, x2.x, a2); a2 = fmaf(w2.y, x2.y, a2);
        a2 = fmaf(w2.z, x2.z, a2); a2 = fmaf(w2.w, x2.w, a2);
        a3 = fmaf(w3.x, x3.x, a3); a3 = fmaf(w3.y, x3.y, a3);
        a3 = fmaf(w3.z, x3.z, a3); a3 = fmaf(w3.w, x3.w, a3);
    }
    return (a0 + a1) + (a2 + a3);
}
// row of 8192 floats: first 4096 dot X1, second 4096 dot X2
__device__ __forceinline__ float wdot8192(const float4* __restrict__ W4,
                                          const float4* __restrict__ X1,
                                          const float4* __restrict__ X2, int l) {
    float a0 = 0.f, a1 = 0.f, a2 = 0.f, a3 = 0.f;
#pragma unroll
    for (int i = 0; i < 16; i += 4) {
        float4 w0 = W4[(i + 0) * 64 + l], x0 = X1[(i + 0) * 64 + l];
        float4 w1 = W4[(i + 1) * 64 + l], x1 = X1[(i + 1) * 64 + l];
        float4 w2 = W4[(i + 2) * 64 + l], x2 = X1[(i + 2) * 64 + l];
        float4 w3 = W4[(i + 3) * 64 + l], x3 = X1[(i + 3) * 64 + l];
        a0 = fmaf(w0.x, x0.x, a0); a0 = fmaf(w0.y, x0.y, a0);
        a0 = fmaf(w0.z, x0.z, a0); a0 = fmaf(w0.w, x0.w, a0);
        a1 = fmaf(w1.x, x1.x, a1); a1 = fmaf(w1.y, x1.y, a1);
        a1 = fmaf(w1.z, x1.z, a1); a1 = fmaf(w1.w, x1.w, a1);
        a2 = fmaf(w2.x, x2.x, a2); a2 = fmaf(w2.y, x2.y, a2);
        a2 = fmaf(w2.z, x2.z, a2); a2 = fmaf(w2.w, x2.w, a2);
        a3 = fmaf(w3.x, x3.x, a3); a3 = fmaf(w3.y, x3.y, a3);
        a3 = fmaf(w3.z, x3.z, a3); a3 = fmaf(w3.w, x3.w, a3);
    }
#pragma unroll
    for (int i = 16; i < 32; i += 4) {
        float4 w0 = W4[(i + 0) * 64 + l], x0 = X2[(i - 16) * 64 + l];
        float4 w1 = W4[(i + 1) * 64 + l], x1 = X2[(i - 15) * 64 + l];
        float4 w2 = W4[(i + 2) * 64 + l], x2 = X2[(i - 14) * 64 + l];
        float4 w3 = W4[(i + 3) * 64 + l], x3 = X2[(i - 13) * 64 + l];
        a0 = fmaf(w0.x, x0.x, a0); a0 = fmaf(w0.y, x0.y, a0);
        a0 = fmaf(w0.z, x0.z, a0); a0 = fmaf(w0.w, x0.w, a0);
        a1 = fmaf(w1.x, x1.x, a1); a1 = fmaf(w1.y, x1.y, a1);
        a1 = fmaf(w1.z, x1.z, a1); a1 = fmaf(w1.w, x1.w, a1);
        a2 = fmaf(w2.x, x2.x, a2); a2 = fmaf(w2.y, x2.y, a2);
        a2 = fmaf(w2.z, x2.z, a2); a2 = fmaf(w2.w, x2.w, a2);
        a3 = fmaf(w3.x, x3.x, a3); a3 = fmaf(w3.y, x3.y, a3);
        a3 = fmaf(w3.z, x3.z, a3); a3 = fmaf(w3.w, x3.w, a3);
    }
    return (a0 + a1) + (a2 + a3);
}

// hh row r (wave-level): ghh[r] = W_hh[r]·h + b_ih[r] + b_hh[r]
__device__ __forceinline__ void hh_row_wave(
    int r, const float* __restrict__ Whh, const float* __restrict__ bih,
    const float* __restrict__ bhh, const float4* __restrict__ H4,
    float* __restrict__ ghh, int l)
{
    float v = wdot4096(reinterpret_cast<const float4*>(Whh + (size_t)r * HD), H4, l);
    v = wave_sum(v);
    if (l == 0) ghh[r] = v + bih[r] + bhh[r];
}

// ---------------- K1: attn logits (2048 rows, 512 blocks) + hh rows [0,4096) (1024 blocks) ----
__global__ __launch_bounds__(256) void k1_attn_hh(
    const float* __restrict__ Wattn, const float* __restrict__ battn,
    const float* __restrict__ emb, const int* __restrict__ token,
    const float* __restrict__ h,
    const float* __restrict__ Whh, const float* __restrict__ bih,
    const float* __restrict__ bhh,
    float* __restrict__ attn_logits, float* __restrict__ ghh)
{
    const int bx = blockIdx.x;
    const int wid = threadIdx.x >> 6, l = threadIdx.x & 63;
    const float4* H4 = reinterpret_cast<const float4*>(h);
    if (bx < 512) {
        const int r = bx * 4 + wid;
        const float4* E1 = reinterpret_cast<const float4*>(emb + (size_t)token[0] * HD);
        float v = wdot8192(reinterpret_cast<const float4*>(Wattn + (size_t)r * 8192), E1, H4, l);
        v = wave_sum(v);
        if (l == 0) attn_logits[r] = v + battn[r];
    } else {
        hh_row_wave((bx - 512) * 4 + wid, Whh, bih, bhh, H4, ghh, l);
    }
}

// ---------------- K2: softmax+ctx (65 blocks) + hh rows [4096,10240) (1536 blocks) --------
__global__ __launch_bounds__(256) void k2_ctx_hh(
    const float* __restrict__ logits, const float* __restrict__ enc,
    const float* __restrict__ Whh, const float* __restrict__ bih,
    const float* __restrict__ bhh, const float* __restrict__ h,
    float* __restrict__ ctx, float* __restrict__ attn_out, float* __restrict__ ghh)
{
    const int bx = blockIdx.x;
    const int t = threadIdx.x;
    if (bx <= 64) {
        // redundant softmax per block (2048 logits from L2)
        __shared__ float sm[4];
        float vals[8];
        float m = -INFINITY;
#pragma unroll
        for (int i = 0; i < 8; ++i) { vals[i] = logits[i * 256 + t]; m = fmaxf(m, vals[i]); }
        m = block_max256(m, sm);
        float s = 0.f;
#pragma unroll
        for (int i = 0; i < 8; ++i) { vals[i] = expf(vals[i] - m); s += vals[i]; }
        s = block_sum256(s, sm);
        const float inv = 1.f / s;
        if (bx == 64) {
#pragma unroll
            for (int i = 0; i < 8; ++i) attn_out[i * 256 + t] = vals[i] * inv;
            return;
        }
        __shared__ float smw[2048];
#pragma unroll
        for (int i = 0; i < 8; ++i) smw[i * 256 + t] = vals[i] * inv;
        __syncthreads();
        // block bx covers 64 cols (16 float4): thread rg = t>>4 (128 rows each), cc = t&15
        const int rg = t >> 4;
        const int cc = t & 15;
        const int col4 = bx * 16 + cc;
        const float4* E = reinterpret_cast<const float4*>(enc);
        float4 acc = make_float4(0.f, 0.f, 0.f, 0.f);
        const int k0 = rg * 128;
#pragma unroll 8
        for (int k = k0; k < k0 + 128; ++k) {
            float wv = smw[k];
            float4 ev = E[(size_t)k * 1024 + col4];
            acc.x = fmaf(wv, ev.x, acc.x); acc.y = fmaf(wv, ev.y, acc.y);
            acc.z = fmaf(wv, ev.z, acc.z); acc.w = fmaf(wv, ev.w, acc.w);
        }
        __shared__ float4 red[16][16];
        red[rg][cc] = acc;
        __syncthreads();
        if (t < 16) {
            float4 s2 = red[0][t];
#pragma unroll
            for (int k = 1; k < 16; ++k) {
                float4 v = red[k][t];
                s2.x += v.x; s2.y += v.y; s2.z += v.z; s2.w += v.w;
            }
            reinterpret_cast<float4*>(ctx)[bx * 16 + t] = s2;
        }
    } else {
        const int wid = t >> 6, l = t & 63;
        hh_row_wave(4096 + (bx - 65) * 4 + wid, Whh, bih, bhh,
                    reinterpret_cast<const float4*>(h), ghh, l);
    }
}

// ---------------- K3: comb (4096 rows, 1024 blocks) + hh rows [10240,16384) (1536 blocks) ----
__global__ __launch_bounds__(256) void k3_comb_hh(
    const float* __restrict__ W, const float* __restrict__ bias,
    const float* __restrict__ emb, const int* __restrict__ token,
    const float* __restrict__ ctx,
    const float* __restrict__ Whh, const float* __restrict__ bih,
    const float* __restrict__ bhh, const float* __restrict__ h,
    float* __restrict__ xvec, float* __restrict__ ghh)
{
    const int bx = blockIdx.x;
    const int wid = threadIdx.x >> 6, l = threadIdx.x & 63;
    if (bx < 1024) {
        const int r = bx * 4 + wid;
        const float4* E1 = reinterpret_cast<const float4*>(emb + (size_t)token[0] * HD);
        const float4* C4 = reinterpret_cast<const float4*>(ctx);
        float v = wdot8192(reinterpret_cast<const float4*>(W + (size_t)r * 8192), E1, C4, l);
        v = wave_sum(v);
        if (l == 0) xvec[r] = fmaxf(v + bias[r], 0.f);
    } else {
        hh_row_wave(10240 + (bx - 1024) * 4 + wid, Whh, bih, bhh,
                    reinterpret_cast<const float4*>(h), ghh, l);
    }
}

// ---------------- K4: gates_ih (one gate row per wave) + LSTM cell ----------------
__global__ __launch_bounds__(256) void k4_ih_cell(
    const float* __restrict__ Wih, const float* __restrict__ ghh,
    const float* __restrict__ x, const float* __restrict__ c,
    float* __restrict__ out /* d_out base */)
{
    const int j = blockIdx.x;   // cell index 0..4095
    const int g = threadIdx.x >> 6, l = threadIdx.x & 63;
    const float4* X = reinterpret_cast<const float4*>(x);
    float v = wdot4096(reinterpret_cast<const float4*>(Wih + (size_t)(g * HD + j) * HD), X, l);
    v = wave_sum(v);
    __shared__ float sm[4];
    if (l == 0) sm[g] = v + ghh[g * HD + j];
    __syncthreads();
    if (threadIdx.x == 0) {
        float gi = sm[0], gf = sm[1], gg = sm[2], go = sm[3];
        float si = 1.f / (1.f + expf(-gi));
        float sf = 1.f / (1.f + expf(-gf));
        float so = 1.f / (1.f + expf(-go));
        float cn = sf * c[j] + si * tanhf(gg);
        float hn = so * tanhf(cn);
        out[HD + j] = hn;       // h_new
        out[2 * HD + j] = cn;   // c_new
    }
}

// ---------------- K5: logits = W_out · h_new + b_out (one row per wave) ----------------
__global__ __launch_bounds__(256) void k5_out(
    const float* __restrict__ W, const float* __restrict__ bias,
    const float* __restrict__ x, float* __restrict__ out)
{
    const int r = blockIdx.x * 4 + (threadIdx.x >> 6);
    const int l = threadIdx.x & 63;
    float v = wdot4096(reinterpret_cast<const float4*>(W + (size_t)r * HD),
                       reinterpret_cast<const float4*>(x), l);
    v = wave_sum(v);
    if (l == 0) out[r] = v + bias[r];
}

// ---------------- K6: log_softmax over 4096 (1024 threads) ----------------
__global__ __launch_bounds__(1024) void k6_logsoftmax(
    const float* __restrict__ logits, float* __restrict__ out)
{
    __shared__ float sm[16];
    const int t = threadIdx.x;
    float vals[4];
    float m = -INFINITY;
#pragma unroll
    for (int i = 0; i < 4; ++i) { vals[i] = logits[i * 1024 + t]; m = fmaxf(m, vals[i]); }
    m = wave_max(m);
    if ((t & 63) == 0) sm[t >> 6] = m;
    __syncthreads();
    float mm = -INFINITY;
#pragma unroll
    for (int k = 0; k < 16; ++k) mm = fmaxf(mm, sm[k]);
    __syncthreads();
    float s = 0.f;
#pragma unroll
    for (int i = 0; i < 4; ++i) s += expf(vals[i] - mm);
    s = wave_sum(s);
    if ((t & 63) == 0) sm[t >> 6] = s;
    __syncthreads();
    float ss = 0.f;
#pragma unroll
    for (int k = 0; k < 16; ++k) ss += sm[k];
    float lse = mm + logf(ss);
#pragma unroll
    for (int i = 0; i < 4; ++i) out[i * 1024 + t] = vals[i] - lse;
}

extern "C" void kernel_launch(void* const* d_in, const int* in_sizes, int n_in,
                              void* d_out, int out_size, void* d_ws, size_t ws_size,
                              hipStream_t stream)
{
    const int*   token  = (const int*)  d_in[0];
    const float* h      = (const float*)d_in[1];
    const float* c      = (const float*)d_in[2];
    const float* enc    = (const float*)d_in[3];
    const float* emb    = (const float*)d_in[4];
    const float* W_attn = (const float*)d_in[5];
    const float* b_attn = (const float*)d_in[6];
    const float* W_comb = (const float*)d_in[7];
    const float* b_comb = (const float*)d_in[8];
    const float* W_ih   = (const float*)d_in[9];
    const float* W_hh   = (const float*)d_in[10];
    const float* b_ih   = (const float*)d_in[11];
    const float* b_hh   = (const float*)d_in[12];
    const float* W_out  = (const float*)d_in[13];
    const float* b_out  = (const float*)d_in[14];
    float* out = (float*)d_out;  // [logp 4096 | h_new 4096 | c_new 4096 | attn_w 2048]

    // ws layout (floats)
    float* ws          = (float*)d_ws;
    float* attn_logits = ws;               // 2048
    float* ghh         = ws + 2048;        // 16384
    float* ctx         = ws + 18432;       // 4096
    float* xvec        = ws + 22528;       // 4096
    float* logits      = ws + 26624;       // 4096

    // K1: attn logits (64 MB) + hh rows 0..4095 (64 MB)
    k1_attn_hh<<<512 + 1024, 256, 0, stream>>>(
        W_attn, b_attn, emb, token, h, W_hh, b_ih, b_hh, attn_logits, ghh);
    // K2: softmax + coalesced ctx (32 MB) + attn_w writer + hh rows 4096..10239 (96 MB)
    k2_ctx_hh<<<65 + 1536, 256, 0, stream>>>(
        attn_logits, enc, W_hh, b_ih, b_hh, h, ctx, out + 3 * HD, ghh);
    // K3: comb (128 MB) + hh rows 10240..16383 (96 MB)
    k3_comb_hh<<<1024 + 1536, 256, 0, stream>>>(
        W_comb, b_comb, emb, token, ctx, W_hh, b_ih, b_hh, h, xvec, ghh);
    // K4: gates_ih + LSTM cell (256 MB); writes h_new/c_new to d_out
    k4_ih_cell<<<HD, 256, 0, stream>>>(W_ih, ghh, xvec, c, out);
    // K5: logits = W_out @ h_new (64 MB)
    k5_out<<<1024, 256, 0, stream>>>(W_out, b_out, out + HD, logits);
    // K6: log_softmax -> logp
    k6_logsoftmax<<<1, 1024, 0, stream>>>(logits, out);
}